// Round 1
// baseline (720.218 us; speedup 1.0000x reference)
//
#include <hip/hip_runtime.h>
#include <cstdint>

// Problem constants (fixed by the reference)
#define BATCH  64
#define NATOMS 1024
#define DEG    5       // max degree / edges per atom
#define FIN    256     // atom feature dim
#define OOUT   256     // output dim
#define NB     6       // bond feature dim
#define KDIM   262     // FIN + NB
#define KPAD   288     // 9 * 32, zero-padded K
#define MT     32      // atoms per block tile
#define KT     32      // k tile staged in LDS

// ~99.5% of atoms have degree 5 (edges ~ randint(-1,1024)); we run a proper
// shared-weight GEMM with degW[5] for the tile and overwrite the rare
// degree!=5 rows with a per-row fallback using the correct weight matrix.
__global__ __launch_bounds__(256, 2)
void nfp_conv_kernel(const float* __restrict__ atoms,
                     const float* __restrict__ bonds,
                     const int*   __restrict__ edges,
                     const float* __restrict__ degW,
                     const float* __restrict__ bias,
                     float* __restrict__ out)
{
    __shared__ float feats[MT * KPAD];   // 36864 B, rows zero-padded past k=261
    __shared__ float wtile[KT * OOUT];   // 32768 B
    __shared__ int   edg[MT * DEG];
    __shared__ int   deg_lds[MT];
    __shared__ int   odd_list[MT];
    __shared__ int   odd_cnt;
    __shared__ float b_lds[OOUT];

    const int tid   = threadIdx.x;
    const int bid   = blockIdx.x;
    const int batch = bid >> 5;          // 32 tiles per batch image
    const int a0    = (bid & 31) * MT;

    const size_t atom_base = (size_t)batch * NATOMS;

    // ---- stage bias, edges; compute degrees; collect odd (deg != 5) rows ----
    b_lds[tid] = bias[tid];
    if (tid == 0) odd_cnt = 0;
    if (tid < MT * DEG) {
        const int m = tid / DEG, d = tid % DEG;
        edg[tid] = edges[(atom_base + a0 + m) * DEG + d];
    }
    __syncthreads();
    if (tid < MT) {
        int dc = 0;
        #pragma unroll
        for (int d = 0; d < DEG; ++d) dc += (edg[tid * DEG + d] != -1) ? 1 : 0;
        deg_lds[tid] = dc;
        if (dc != DEG) {
            const int idx = atomicAdd(&odd_cnt, 1);
            odd_list[idx] = tid;
        }
    }
    __syncthreads();

    // ---- build feats[m][k]: self + neighbor sum (k<256), bond sums (256..261), pad 0 ----
    {
        const int f = tid;                        // 0..255, coalesced across the row
        for (int m = 0; m < MT; ++m) {
            float v = atoms[(atom_base + a0 + m) * FIN + f];
            #pragma unroll
            for (int d = 0; d < DEG; ++d) {
                const int e = edg[m * DEG + d];   // wave-uniform branch
                if (e >= 0) v += atoms[(atom_base + e) * FIN + f];
            }
            feats[m * KPAD + f] = v;
        }
        #pragma unroll
        for (int t = 0; t < 4; ++t) {
            const int idx = t * 256 + tid;        // covers MT*32 tail slots
            const int m  = idx >> 5;
            const int kk = idx & 31;
            float v = 0.f;
            if (kk < NB) {
                const size_t bb = (atom_base + a0 + m) * (size_t)(DEG * NB);
                #pragma unroll
                for (int d = 0; d < DEG; ++d) v += bonds[bb + d * NB + kk];
            }
            feats[m * KPAD + FIN + kk] = v;
        }
    }

    // ---- main GEMM: tile(32 atoms x 256 outs) @ degW[5], K staged in LDS ----
    const float* __restrict__ W5 = degW + (size_t)DEG * KDIM * OOUT;
    float acc[4][8];
    #pragma unroll
    for (int i = 0; i < 4; ++i)
        #pragma unroll
        for (int j = 0; j < 8; ++j) acc[i][j] = 0.f;

    const int tx = tid & 31;   // output lane group
    const int ty = tid >> 5;   // atom group (0..7), 4 atoms each

    for (int kt = 0; kt < KPAD; kt += KT) {
        __syncthreads();
        #pragma unroll
        for (int t = 0; t < KT; ++t) {
            const int k = kt + t;
            wtile[t * OOUT + tid] = (k < KDIM) ? W5[(size_t)k * OOUT + tid] : 0.f;
        }
        __syncthreads();
        #pragma unroll 4
        for (int r = 0; r < KT; ++r) {
            float a_frag[4];
            #pragma unroll
            for (int i = 0; i < 4; ++i)
                a_frag[i] = feats[(ty * 4 + i) * KPAD + kt + r];  // broadcast read
            float w_frag[8];
            #pragma unroll
            for (int j = 0; j < 8; ++j)
                w_frag[j] = wtile[r * OOUT + tx + j * 32];        // conflict-free
            #pragma unroll
            for (int i = 0; i < 4; ++i)
                #pragma unroll
                for (int j = 0; j < 8; ++j)
                    acc[i][j] += a_frag[i] * w_frag[j];
        }
    }

    // ---- epilogue: bias + sigmoid + store for degree-5 rows ----
    #pragma unroll
    for (int i = 0; i < 4; ++i) {
        const int m = ty * 4 + i;
        if (deg_lds[m] == DEG) {
            const size_t row = (atom_base + a0 + m) * (size_t)OOUT;
            #pragma unroll
            for (int j = 0; j < 8; ++j) {
                const int o = tx + j * 32;
                const float x = acc[i][j] + b_lds[o];
                out[row + o] = 1.f / (1.f + __expf(-x));
            }
        }
    }

    // ---- fallback: rare degree!=5 rows, per-row matvec with correct weights ----
    const int ocnt = odd_cnt;
    for (int i = 0; i < ocnt; ++i) {
        const int m = odd_list[i];
        const int d = deg_lds[m];
        const float* __restrict__ W = degW + (size_t)d * KDIM * OOUT;
        float a2 = 0.f;
        for (int k = 0; k < KDIM; ++k)
            a2 += feats[m * KPAD + k] * W[(size_t)k * OOUT + tid];
        const size_t row = (atom_base + a0 + m) * (size_t)OOUT;
        const float x = a2 + b_lds[tid];
        out[row + tid] = 1.f / (1.f + __expf(-x));
    }
}

extern "C" void kernel_launch(void* const* d_in, const int* in_sizes, int n_in,
                              void* d_out, int out_size, void* d_ws, size_t ws_size,
                              hipStream_t stream) {
    const float* atoms = (const float*)d_in[0];
    const float* bonds = (const float*)d_in[1];
    const int*   edges = (const int*)d_in[2];
    const float* degW  = (const float*)d_in[3];
    const float* bias  = (const float*)d_in[4];
    float* out = (float*)d_out;

    const int grid = BATCH * (NATOMS / MT);   // 2048 blocks
    nfp_conv_kernel<<<grid, 256, 0, stream>>>(atoms, bonds, edges, degW, bias, out);
}

// Round 2
// 222.119 us; speedup vs baseline: 3.2425x; 3.2425x over previous
//
#include <hip/hip_runtime.h>
#include <cstdint>

// Problem constants (fixed by the reference)
#define BATCH  64
#define NATOMS 1024
#define DEG    5
#define FIN    256
#define OOUT   256
#define NBF    6
#define KDIM   262          // FIN + NBF
#define KP     288          // padded K (9 x 32) for bf16 feats / Wt
#define MROWS  (BATCH * NATOMS)   // 65536

typedef __attribute__((ext_vector_type(8))) short bf16x8;   // 8 bf16 = 4 VGPR (MFMA A/B frag)
typedef __attribute__((ext_vector_type(4))) float f32x4;    // MFMA C/D frag

__device__ __forceinline__ unsigned short f2bf(float x) {
    unsigned u = __float_as_uint(x);
    u += 0x7fff + ((u >> 16) & 1);          // round-to-nearest-even
    return (unsigned short)(u >> 16);
}
__device__ __forceinline__ float bf2f(unsigned short h) {
    return __uint_as_float(((unsigned)h) << 16);
}
__device__ __forceinline__ float sigmoidf_(float x) {
    return 1.f / (1.f + __expf(-x));
}

// ---------------------------------------------------------------------------
// Kernel 1: degW fp32 [6][262][256] -> Wt bf16 [6][256][288] (transposed,
// k-contiguous, zero-padded past k=261). 442368 elements, trivial.
// ---------------------------------------------------------------------------
__global__ __launch_bounds__(256)
void convert_w_kernel(const float* __restrict__ degW, unsigned short* __restrict__ Wt)
{
    const int idx = blockIdx.x * 256 + threadIdx.x;      // over 6*288*256
    if (idx >= 6 * KP * OOUT) return;
    const int d   = idx / (KP * OOUT);
    const int rem = idx % (KP * OOUT);
    const int k   = rem / OOUT;                           // o fastest -> coalesced read
    const int o   = rem % OOUT;
    const float v = (k < KDIM) ? degW[(size_t)d * KDIM * OOUT + (size_t)k * OOUT + o] : 0.f;
    Wt[(size_t)d * OOUT * KP + (size_t)o * KP + k] = f2bf(v);
}

// ---------------------------------------------------------------------------
// Kernel 2: gather. One wave per atom row: feats[row][0..255] = self +
// sum(neighbors); [256..261] = bond sums; [262..287] = 0. Records odd
// (degree != 5) rows for the fixup pass.
// ---------------------------------------------------------------------------
__global__ __launch_bounds__(256)
void gather_kernel(const float* __restrict__ atoms, const float* __restrict__ bonds,
                   const int* __restrict__ edges, unsigned short* __restrict__ feats,
                   int* __restrict__ odd_list, int* __restrict__ odd_cnt)
{
    const int tid  = threadIdx.x;
    const int lane = tid & 63;
    const int w    = tid >> 6;
    const int row  = blockIdx.x * 4 + w;                  // [0, 65536)
    const int batch = row >> 10;

    const float4* arow = (const float4*)(atoms + (size_t)row * FIN);
    float4 v = arow[lane];                                 // coalesced 16B/lane
    int deg = 0;
    #pragma unroll
    for (int d = 0; d < DEG; ++d) {
        const int e = edges[row * DEG + d];                // wave-uniform
        if (e >= 0) {
            ++deg;
            const float4* nrow = (const float4*)(atoms + ((size_t)(batch << 10) + e) * FIN);
            const float4 nv = nrow[lane];
            v.x += nv.x; v.y += nv.y; v.z += nv.z; v.w += nv.w;
        }
    }
    ushort4 us;
    us.x = f2bf(v.x); us.y = f2bf(v.y); us.z = f2bf(v.z); us.w = f2bf(v.w);
    *(ushort4*)&feats[(size_t)row * KP + lane * 4] = us;   // 8B/lane, aligned

    if (lane < 32) {                                       // k = 256..287 tail
        float bv = 0.f;
        if (lane < NBF) {
            const float* bb = bonds + (size_t)row * (DEG * NBF);
            #pragma unroll
            for (int d = 0; d < DEG; ++d) bv += bb[d * NBF + lane];
        }
        feats[(size_t)row * KP + FIN + lane] = f2bf(bv);
    }
    if (lane == 0 && deg != DEG) {
        const int i = atomicAdd(odd_cnt, 1);               // ~320 total, no contention
        odd_list[i] = (row << 3) | deg;
    }
}

// ---------------------------------------------------------------------------
// Kernel 3: bf16 MFMA GEMM, everyone gets degW[5] (99.5% of atoms are deg 5).
// 128x128 tile, 256 threads = 4 waves in 2x2, each wave 4x4 of 16x16x32 MFMA.
// LDS rows padded to 40 bf16 (80 B) -> 2-way max bank aliasing (free).
// ---------------------------------------------------------------------------
__global__ __launch_bounds__(256, 2)
void gemm_kernel(const unsigned short* __restrict__ feats,
                 const unsigned short* __restrict__ Wt5,
                 const float* __restrict__ bias, float* __restrict__ out)
{
    __shared__ short As[128 * 40];   // 10240 B
    __shared__ short Bs[128 * 40];   // 10240 B

    const int tid  = threadIdx.x;
    const int m0   = (blockIdx.x >> 1) * 128;
    const int n0   = (blockIdx.x & 1) * 128;
    const int lane = tid & 63;
    const int wave = tid >> 6;
    const int wm   = (wave & 1) * 64;
    const int wn   = (wave >> 1) * 64;
    const int fr   = lane & 15;      // frag row/col index
    const int q    = lane >> 4;      // quad -> k-chunk

    f32x4 acc[4][4];
    #pragma unroll
    for (int i = 0; i < 4; ++i)
        #pragma unroll
        for (int j = 0; j < 4; ++j)
            acc[i][j] = (f32x4){0.f, 0.f, 0.f, 0.f};

    const unsigned short* Ag = feats + (size_t)m0 * KP;
    const unsigned short* Bg = Wt5  + (size_t)n0 * KP;

    for (int kt = 0; kt < KP; kt += 32) {
        __syncthreads();
        #pragma unroll
        for (int p = 0; p < 2; ++p) {                       // 128 rows x 32 k each
            const int idx = p * 256 + tid;
            const int r = idx >> 2, c = (idx & 3) * 8;
            *(uint4*)&As[r * 40 + c] = *(const uint4*)&Ag[(size_t)r * KP + kt + c];
            *(uint4*)&Bs[r * 40 + c] = *(const uint4*)&Bg[(size_t)r * KP + kt + c];
        }
        __syncthreads();

        bf16x8 af[4], bf[4];
        #pragma unroll
        for (int i = 0; i < 4; ++i)
            af[i] = *(const bf16x8*)&As[(wm + i * 16 + fr) * 40 + q * 8];  // ds_read_b128
        #pragma unroll
        for (int j = 0; j < 4; ++j)
            bf[j] = *(const bf16x8*)&Bs[(wn + j * 16 + fr) * 40 + q * 8];
        #pragma unroll
        for (int i = 0; i < 4; ++i)
            #pragma unroll
            for (int j = 0; j < 4; ++j)
                acc[i][j] = __builtin_amdgcn_mfma_f32_16x16x32_bf16(af[i], bf[j], acc[i][j], 0, 0, 0);
    }

    // epilogue: C/D mapping col = lane&15, row = (lane>>4)*4 + reg  [m89/m91]
    #pragma unroll
    for (int j = 0; j < 4; ++j) {
        const int gn = n0 + wn + j * 16 + fr;
        const float bj = bias[gn];
        #pragma unroll
        for (int i = 0; i < 4; ++i) {
            #pragma unroll
            for (int r = 0; r < 4; ++r) {
                const int gm = m0 + wm + i * 16 + q * 4 + r;
                out[(size_t)gm * OOUT + gn] = sigmoidf_(acc[i][j][r] + bj);
            }
        }
    }
}

// ---------------------------------------------------------------------------
// Kernel 4: fixup the rare degree != 5 rows with the correct weight matrix.
// One block per odd atom (grid-stride); thread = one output column.
// ---------------------------------------------------------------------------
__global__ __launch_bounds__(256)
void fixup_kernel(const unsigned short* __restrict__ feats, const float* __restrict__ degW,
                  const float* __restrict__ bias, const int* __restrict__ odd_list,
                  const int* __restrict__ odd_cnt, float* __restrict__ out)
{
    const int cnt = *odd_cnt;
    const int tid = threadIdx.x;
    for (int i = blockIdx.x; i < cnt; i += gridDim.x) {
        const int packed = odd_list[i];
        const int row = packed >> 3;
        const int d   = packed & 7;
        const float* __restrict__ W = degW + (size_t)d * KDIM * OOUT;
        float acc = 0.f;
        for (int k = 0; k < KDIM; ++k)
            acc += bf2f(feats[(size_t)row * KP + k]) * W[(size_t)k * OOUT + tid];
        out[(size_t)row * OOUT + tid] = sigmoidf_(acc + bias[tid]);
    }
}

// ---------------------------------------------------------------------------
// Fallback (R1 fp32 kernel) if ws_size is too small for the bf16 pipeline.
// ---------------------------------------------------------------------------
#define MT  32
#define KT  32
#define KPAD 288
__global__ __launch_bounds__(256, 2)
void nfp_conv_fallback(const float* __restrict__ atoms, const float* __restrict__ bonds,
                       const int* __restrict__ edges, const float* __restrict__ degW,
                       const float* __restrict__ bias, float* __restrict__ out)
{
    __shared__ float feats[MT * KPAD];
    __shared__ float wtile[KT * OOUT];
    __shared__ int   edg[MT * DEG];
    __shared__ int   deg_lds[MT];
    __shared__ int   odd_list[MT];
    __shared__ int   odd_cnt;
    __shared__ float b_lds[OOUT];

    const int tid = threadIdx.x, bid = blockIdx.x;
    const int batch = bid >> 5, a0 = (bid & 31) * MT;
    const size_t atom_base = (size_t)batch * NATOMS;

    b_lds[tid] = bias[tid];
    if (tid == 0) odd_cnt = 0;
    if (tid < MT * DEG) {
        const int m = tid / DEG, d = tid % DEG;
        edg[tid] = edges[(atom_base + a0 + m) * DEG + d];
    }
    __syncthreads();
    if (tid < MT) {
        int dc = 0;
        #pragma unroll
        for (int d = 0; d < DEG; ++d) dc += (edg[tid * DEG + d] != -1) ? 1 : 0;
        deg_lds[tid] = dc;
        if (dc != DEG) { const int idx = atomicAdd(&odd_cnt, 1); odd_list[idx] = tid; }
    }
    __syncthreads();
    {
        const int f = tid;
        for (int m = 0; m < MT; ++m) {
            float v = atoms[(atom_base + a0 + m) * FIN + f];
            #pragma unroll
            for (int d = 0; d < DEG; ++d) {
                const int e = edg[m * DEG + d];
                if (e >= 0) v += atoms[(atom_base + e) * FIN + f];
            }
            feats[m * KPAD + f] = v;
        }
        #pragma unroll
        for (int t = 0; t < 4; ++t) {
            const int idx = t * 256 + tid;
            const int m = idx >> 5, kk = idx & 31;
            float v = 0.f;
            if (kk < NBF) {
                const size_t bb = (atom_base + a0 + m) * (size_t)(DEG * NBF);
                #pragma unroll
                for (int d = 0; d < DEG; ++d) v += bonds[bb + d * NBF + kk];
            }
            feats[m * KPAD + FIN + kk] = v;
        }
    }
    const float* __restrict__ W5 = degW + (size_t)DEG * KDIM * OOUT;
    float acc[4][8];
    #pragma unroll
    for (int i = 0; i < 4; ++i)
        #pragma unroll
        for (int j = 0; j < 8; ++j) acc[i][j] = 0.f;
    const int tx = tid & 31, ty = tid >> 5;
    for (int kt = 0; kt < KPAD; kt += KT) {
        __syncthreads();
        #pragma unroll
        for (int t = 0; t < KT; ++t) {
            const int k = kt + t;
            wtile[t * OOUT + tid] = (k < KDIM) ? W5[(size_t)k * OOUT + tid] : 0.f;
        }
        __syncthreads();
        #pragma unroll 4
        for (int r = 0; r < KT; ++r) {
            float a_frag[4];
            #pragma unroll
            for (int i = 0; i < 4; ++i) a_frag[i] = feats[(ty * 4 + i) * KPAD + kt + r];
            float w_frag[8];
            #pragma unroll
            for (int j = 0; j < 8; ++j) w_frag[j] = wtile[r * OOUT + tx + j * 32];
            #pragma unroll
            for (int i = 0; i < 4; ++i)
                #pragma unroll
                for (int j = 0; j < 8; ++j) acc[i][j] += a_frag[i] * w_frag[j];
        }
    }
    #pragma unroll
    for (int i = 0; i < 4; ++i) {
        const int m = ty * 4 + i;
        if (deg_lds[m] == DEG) {
            const size_t row = (atom_base + a0 + m) * (size_t)OOUT;
            #pragma unroll
            for (int j = 0; j < 8; ++j) {
                const int o = tx + j * 32;
                out[row + o] = sigmoidf_(acc[i][j] + b_lds[o]);
            }
        }
    }
    const int ocnt = odd_cnt;
    for (int i = 0; i < ocnt; ++i) {
        const int m = odd_list[i], d = deg_lds[m];
        const float* __restrict__ W = degW + (size_t)d * KDIM * OOUT;
        float a2 = 0.f;
        for (int k = 0; k < KDIM; ++k) a2 += feats[m * KPAD + k] * W[(size_t)k * OOUT + tid];
        const size_t row = (atom_base + a0 + m) * (size_t)OOUT;
        out[row + tid] = sigmoidf_(a2 + b_lds[tid]);
    }
}

// ---------------------------------------------------------------------------
extern "C" void kernel_launch(void* const* d_in, const int* in_sizes, int n_in,
                              void* d_out, int out_size, void* d_ws, size_t ws_size,
                              hipStream_t stream) {
    const float* atoms = (const float*)d_in[0];
    const float* bonds = (const float*)d_in[1];
    const int*   edges = (const int*)d_in[2];
    const float* degW  = (const float*)d_in[3];
    const float* bias  = (const float*)d_in[4];
    float* out = (float*)d_out;

    // ws layout (bytes)
    const size_t FEATS_BYTES = (size_t)MROWS * KP * 2;              // 37,748,736
    const size_t WT_OFF      = FEATS_BYTES;
    const size_t WT_BYTES    = (size_t)6 * OOUT * KP * 2;           // 884,736
    const size_t ODD_OFF     = WT_OFF + WT_BYTES;
    const size_t ODD_BYTES   = (size_t)MROWS * 4;
    const size_t CNT_OFF     = ODD_OFF + ODD_BYTES;
    const size_t NEEDED      = CNT_OFF + 16;

    if (ws_size < NEEDED) {   // safety net: fp32 path needs no workspace
        nfp_conv_fallback<<<BATCH * (NATOMS / MT), 256, 0, stream>>>(
            atoms, bonds, edges, degW, bias, out);
        return;
    }

    unsigned short* feats = (unsigned short*)d_ws;
    unsigned short* Wt    = (unsigned short*)((char*)d_ws + WT_OFF);
    int* odd_list         = (int*)((char*)d_ws + ODD_OFF);
    int* odd_cnt          = (int*)((char*)d_ws + CNT_OFF);

    hipMemsetAsync(odd_cnt, 0, 4, stream);
    convert_w_kernel<<<(6 * KP * OOUT) / 256, 256, 0, stream>>>(degW, Wt);
    gather_kernel<<<MROWS / 4, 256, 0, stream>>>(atoms, bonds, edges, feats, odd_list, odd_cnt);
    gemm_kernel<<<(MROWS / 128) * 2, 256, 0, stream>>>(
        feats, Wt + (size_t)5 * OOUT * KP, bias, out);
    fixup_kernel<<<512, 256, 0, stream>>>(feats, degW, bias, odd_list, odd_cnt, out);
}